// Round 3
// baseline (1996.403 us; speedup 1.0000x reference)
//
#include <hip/hip_runtime.h>

typedef _Float16 half_t;

#define N_SRCN 50000
#define N_DSTN 50000
#define NE     1600000
#define IN_DIM 128
#define OUT_DIMN 128
#define EDGE_DIMN 64
#define NHEAD  4
#define HDIM   32

// ---------------------------------------------------------------------------
// Workspace layout — 15,206,144 bytes total. R1 (54.4MB) and R2 (21.2MB) both
// showed: call 1 correct, all later calls consistently wrong ~0.2 => OOB writes
// past end of d_ws corrupted the harness's pristine input copies. Conclusion:
// ws_size < 21.2MB (likely 16MiB). This layout stays under 16MiB and drops the
// CSR kernels entirely (atomic aggregation instead).
//   hs      half[6,400,000] @ 0           (12,800,000)  h_src @ W_src, fp16
//   esrc    f32[200,000]    @ 12,800,000  (   800,000)  per-src logits [N,4]
//   edstl   f32[200,000]    @ 13,600,000  (   800,000)  per-dst logits [N,4]
//   esum    f32[200,000]    @ 14,400,000  (   800,000)  softmax denominators
//   c_src   f32[512]        @ 15,200,000  (     2,048)
//   c_dst   f32[512]        @ 15,202,048  (     2,048)
//   c_edge  f32[256]        @ 15,204,096  (     1,024)  interleaved [k*4+h]
//   c_edgeH f32[256]        @ 15,205,120  (     1,024)  head-major  [h*64+k]
// ---------------------------------------------------------------------------

// K1: fold attention vectors through weights.
// c[k*4+h] = sum_d W[k][h*32+d] * a[h][d]; c_edge also stored head-major.
__global__ __launch_bounds__(512) void k_combine(
    const float* __restrict__ Wsrc, const float* __restrict__ Wdst,
    const float* __restrict__ Wedge,
    const float* __restrict__ asrc, const float* __restrict__ adst,
    const float* __restrict__ aedge,
    float* __restrict__ c_src, float* __restrict__ c_dst,
    float* __restrict__ c_edge, float* __restrict__ c_edgeH) {
    int t = threadIdx.x;           // k = t>>2 (0..127), h = t&3
    int k = t >> 2, h = t & 3;
    float s1 = 0.f, s2 = 0.f;
    #pragma unroll
    for (int d = 0; d < HDIM; ++d) {
        s1 += Wsrc[k * OUT_DIMN + h * HDIM + d] * asrc[h * HDIM + d];
        s2 += Wdst[k * OUT_DIMN + h * HDIM + d] * adst[h * HDIM + d];
    }
    c_src[t] = s1;
    c_dst[t] = s2;
    if (t < EDGE_DIMN * NHEAD) {   // k = 0..63
        float s3 = 0.f;
        #pragma unroll
        for (int d = 0; d < HDIM; ++d)
            s3 += Wedge[k * OUT_DIMN + h * HDIM + d] * aedge[h * HDIM + d];
        c_edge[t] = s3;            // [k*4+h]
        c_edgeH[h * EDGE_DIMN + k] = s3;  // [h*64+k]
    }
}

// K2: hs = h_src @ W_src, stored fp16. Tile M=64, N=128 (full), K chunked 64.
__global__ __launch_bounds__(256) void k_gemm_hs(
    const float* __restrict__ A, const float* __restrict__ W,
    half_t* __restrict__ C, int M) {
    __shared__ float As[64][68];
    __shared__ float Ws[64][132];
    int t = threadIdx.x;
    int tx = t & 15, ty = t >> 4;
    int rowbase = blockIdx.x * 64;
    float acc[4][8];
    #pragma unroll
    for (int i = 0; i < 4; ++i)
        #pragma unroll
        for (int j = 0; j < 8; ++j) acc[i][j] = 0.f;

    for (int kc = 0; kc < IN_DIM; kc += 64) {
        #pragma unroll
        for (int p = 0; p < 4; ++p) {          // A tile: 64x64
            int flat = p * 1024 + t * 4;
            int r = flat >> 6, ck = flat & 63;
            float4 v = make_float4(0.f, 0.f, 0.f, 0.f);
            if (rowbase + r < M)
                v = *(const float4*)(A + (size_t)(rowbase + r) * IN_DIM + kc + ck);
            *(float4*)(&As[r][ck]) = v;
        }
        #pragma unroll
        for (int p = 0; p < 8; ++p) {          // W tile: 64x128
            int flat = p * 1024 + t * 4;
            int kk = flat >> 7, col = flat & 127;
            *(float4*)(&Ws[kk][col]) =
                *(const float4*)(W + (size_t)(kc + kk) * OUT_DIMN + col);
        }
        __syncthreads();
        #pragma unroll
        for (int k = 0; k < 64; ++k) {
            float a[4], b[8];
            #pragma unroll
            for (int i = 0; i < 4; ++i) a[i] = As[ty * 4 + i][k];
            #pragma unroll
            for (int j = 0; j < 8; ++j) b[j] = Ws[k][tx + j * 16];
            #pragma unroll
            for (int i = 0; i < 4; ++i)
                #pragma unroll
                for (int j = 0; j < 8; ++j) acc[i][j] += a[i] * b[j];
        }
        __syncthreads();
    }
    #pragma unroll
    for (int i = 0; i < 4; ++i) {
        int row = rowbase + ty * 4 + i;
        if (row < M) {
            #pragma unroll
            for (int j = 0; j < 8; ++j)
                C[(size_t)row * OUT_DIMN + tx + j * 16] = (half_t)acc[i][j];
        }
    }
}

// K3: node logits  out[row][h] = sum_k X[row][k] * c[k*4+h]. One wave per row.
__global__ __launch_bounds__(256) void k_node_logits(
    const float* __restrict__ X, const float* __restrict__ c,
    float* __restrict__ outl, int N) {
    int row = blockIdx.x * 4 + (threadIdx.x >> 6);
    int l = threadIdx.x & 63;
    if (row >= N) return;
    float x0 = X[(size_t)row * IN_DIM + l];
    float x1 = X[(size_t)row * IN_DIM + 64 + l];
    #pragma unroll
    for (int h = 0; h < NHEAD; ++h) {
        float s = x0 * c[l * 4 + h] + x1 * c[(64 + l) * 4 + h];
        #pragma unroll
        for (int off = 32; off; off >>= 1) s += __shfl_xor(s, off, 64);
        if (l == h) outl[(size_t)row * 4 + h] = s;
    }
}

// K4 (pass A): per-edge logit -> exp -> atomic segment-sum into esum[dst,h].
// Block = 256 threads = 64 edges x 4 heads, edge tile staged in LDS.
// No max-subtraction: logits are bounded (|z| ~< 4), softmax is shift-invariant.
__global__ __launch_bounds__(256) void k_edge_expsum(
    const float* __restrict__ EF,
    const int* __restrict__ srcI, const int* __restrict__ dstI,
    const float* __restrict__ esrc, const float* __restrict__ edstl,
    const float* __restrict__ c_edge, float* __restrict__ esum) {
    __shared__ float Ef[64][68];
    __shared__ float ce[EDGE_DIMN * NHEAD];
    int t = threadIdx.x;
    int eb = blockIdx.x * 64;
    ce[t] = c_edge[t];
    #pragma unroll
    for (int p = 0; p < 4; ++p) {
        int flat = p * 1024 + t * 4;
        int r = flat >> 6, col = flat & 63;
        float4 v = make_float4(0.f, 0.f, 0.f, 0.f);
        if (eb + r < NE)
            v = *(const float4*)(EF + (size_t)(eb + r) * EDGE_DIMN + col);
        *(float4*)(&Ef[r][col]) = v;
    }
    __syncthreads();
    int r = t >> 2, h = t & 3;
    float s = 0.f;
    #pragma unroll
    for (int k4 = 0; k4 < 16; ++k4) {
        float4 v = *(const float4*)(&Ef[r][k4 * 4]);
        s += v.x * ce[(k4 * 4 + 0) * 4 + h] + v.y * ce[(k4 * 4 + 1) * 4 + h]
           + v.z * ce[(k4 * 4 + 2) * 4 + h] + v.w * ce[(k4 * 4 + 3) * 4 + h];
    }
    int e = eb + r;
    if (e < NE) {
        int si = srcI[e], di = dstI[e];
        float z = esrc[(size_t)si * 4 + h] + edstl[(size_t)di * 4 + h] + s;
        z = z > 0.f ? z : 0.2f * z;
        unsafeAtomicAdd(&esum[(size_t)di * 4 + h], __expf(z));
    }
}

// K5 (pass B): one wave per edge. Recompute z (re-reads edge_feat), then
// w = exp(z)/esum and 128 f32 atomics into out. Lane l: group g=l>>4 handles
// head g's dot (float4 + 4 intra-group shuffles), then owns out cols 2l,2l+1.
__global__ __launch_bounds__(256) void k_aggregate_atomic(
    const int* __restrict__ srcI, const int* __restrict__ dstI,
    const float* __restrict__ esrc, const float* __restrict__ edstl,
    const float* __restrict__ ceH, const float* __restrict__ EF,
    const float* __restrict__ esum, const unsigned* __restrict__ hs_u32,
    float* __restrict__ out) {
    int e = blockIdx.x * 4 + (threadIdx.x >> 6);
    if (e >= NE) return;
    int l = threadIdx.x & 63;
    int g = l >> 4, j = l & 15;
    int si = srcI[e], di = dstI[e];

    float4 v  = ((const float4*)(EF + (size_t)e * EDGE_DIMN))[j];
    float4 c4 = ((const float4*)(ceH + g * EDGE_DIMN))[j];
    float s = v.x * c4.x + v.y * c4.y + v.z * c4.z + v.w * c4.w;
    s += __shfl_xor(s, 1, 64);
    s += __shfl_xor(s, 2, 64);
    s += __shfl_xor(s, 4, 64);
    s += __shfl_xor(s, 8, 64);   // all 16 lanes of group g hold head-g dot

    float z = esrc[(size_t)si * 4 + g] + edstl[(size_t)di * 4 + g] + s;
    z = z > 0.f ? z : 0.2f * z;
    float w = __expf(z) / (esum[(size_t)di * 4 + g] + 1e-8f);

    unsigned hp = hs_u32[(size_t)si * 64 + l];   // two fp16 of hs[si][2l..2l+1]
    half_t h0 = ((const half_t*)&hp)[0];
    half_t h1 = ((const half_t*)&hp)[1];
    unsafeAtomicAdd(&out[(size_t)di * OUT_DIMN + 2 * l],     w * (float)h0);
    unsafeAtomicAdd(&out[(size_t)di * OUT_DIMN + 2 * l + 1], w * (float)h1);
}

extern "C" void kernel_launch(void* const* d_in, const int* in_sizes, int n_in,
                              void* d_out, int out_size, void* d_ws, size_t ws_size,
                              hipStream_t stream) {
    const float* h_src     = (const float*)d_in[0];
    const float* h_dst     = (const float*)d_in[1];
    const float* edge_feat = (const float*)d_in[2];
    const int*   eidx      = (const int*)d_in[3];   // [2, E] int32
    const float* Wsrc      = (const float*)d_in[4];
    const float* Wdst      = (const float*)d_in[5];
    const float* Wedge     = (const float*)d_in[6];
    const float* asrc      = (const float*)d_in[7];
    const float* adst      = (const float*)d_in[8];
    const float* aedge     = (const float*)d_in[9];
    float* out = (float*)d_out;

    char* W = (char*)d_ws;
    half_t* hs     = (half_t*)(W + 0);
    float* esrc    = (float*)(W + 12800000);
    float* edstl   = (float*)(W + 13600000);
    float* esum    = (float*)(W + 14400000);
    float* c_src   = (float*)(W + 15200000);
    float* c_dst   = (float*)(W + 15202048);
    float* c_edge  = (float*)(W + 15204096);
    float* c_edgeH = (float*)(W + 15205120);

    const int* srcI = eidx;
    const int* dstI = eidx + NE;

    hipMemsetAsync(esum, 0, N_DSTN * NHEAD * sizeof(float), stream);
    hipMemsetAsync(out, 0, (size_t)out_size * sizeof(float), stream);

    k_combine<<<1, 512, 0, stream>>>(Wsrc, Wdst, Wedge, asrc, adst, aedge,
                                     c_src, c_dst, c_edge, c_edgeH);
    k_gemm_hs<<<(N_SRCN + 63) / 64, 256, 0, stream>>>(h_src, Wsrc, hs, N_SRCN);
    k_node_logits<<<(N_SRCN + 3) / 4, 256, 0, stream>>>(h_src, c_src, esrc, N_SRCN);
    k_node_logits<<<(N_DSTN + 3) / 4, 256, 0, stream>>>(h_dst, c_dst, edstl, N_DSTN);
    k_edge_expsum<<<(NE + 63) / 64, 256, 0, stream>>>(edge_feat, srcI, dstI,
                                                      esrc, edstl, c_edge, esum);
    k_aggregate_atomic<<<(NE + 3) / 4, 256, 0, stream>>>(
        srcI, dstI, esrc, edstl, c_edgeH, edge_feat, esum, (const unsigned*)hs, out);
}